// Round 3
// baseline (260.437 us; speedup 1.0000x reference)
//
#include <hip/hip_runtime.h>
#include <math.h>

// Differentiable-rasterizer forward: scalar sum((render - ref)^2).
// B=2, V=512, F=768, S=256 (derived from in_sizes at runtime).
//
// R3: two kernel nodes total.
//  - k_prep (parallel): face affine coeffs + per-face bbox + tanh(tex) +
//    zeroing of cres/counters (replaces memset node + serial prep).
//  - k_raster (fused): 16x16 pixel tiles x NCHUNK face chunks; per-block
//    bbox cull + ballot-compact (~10x fewer inner-loop face tests), LDS
//    stage survivors, argmax-invz via packed u64 atomicMax; last chunk
//    block per tile does the epilogue/merge; last tile does the final
//    f64 reduction. Device-scope fences + agent-scope atomic loads for
//    cross-XCD visibility (Guideline 16).

#define NCHUNK 4
#define MAXFC  256
#define TILE   16

__global__ __launch_bounds__(256)
void k_prep(const float* __restrict__ verts, const int* __restrict__ faces,
            const float* __restrict__ Kmat, const float* __restrict__ Rmat,
            const float* __restrict__ tvec, const float* __restrict__ texin,
            float4* __restrict__ finner, float4* __restrict__ fepi,
            float4* __restrict__ fbox, float* __restrict__ texd,
            float4* __restrict__ zbase, int nzero4,
            int B, int V, int F, int S, int NBF, int NBT, int NBZ)
{
    int blk = blockIdx.x, tid = threadIdx.x;
    if (blk < NBF) {
        // ---- face blocks: project ALL verts into LDS, then one face/thread
        __shared__ float4 svdat[1024];      // B*V <= 1024 here
        int nv = B * V;
        for (int i = tid; i < nv && i < 1024; i += 256) {
            int b = i / V;
            const float* vp = verts + (size_t)i * 3;
            float vx = vp[0], vy = vp[1], vz = vp[2];
            const float* R  = Rmat + b * 9;
            const float* Kb = Kmat + b * 9;
            const float* tb = tvec + b * 3;
            float c0 = R[0]*vx + R[1]*vy + R[2]*vz + tb[0];
            float c1 = R[3]*vx + R[4]*vy + R[5]*vz + tb[1];
            float c2 = R[6]*vx + R[7]*vy + R[8]*vz + tb[2];
            float z  = c2;
            float zd = z + 1e-9f;
            float xh = c0 / zd;
            float yh = c1 / zd;
            float p0 = xh*Kb[0] + yh*Kb[1] + Kb[2];
            float p1 = xh*Kb[3] + yh*Kb[4] + Kb[5];
            float Sf = (float)S;
            float u = 2.0f * (p0 - 0.5f*Sf) / Sf;
            float v = 2.0f * ((Sf - p1) - 0.5f*Sf) / Sf;
            svdat[i] = make_float4(u, v, z, 0.0f);
        }
        __syncthreads();
        int i = blk * 256 + tid;
        if (i < B * F) {
            int b = i / F;
            const int* fp = faces + (size_t)i * 3;
            float4 p0 = svdat[b*V + fp[0]];
            float4 p1 = svdat[b*V + fp[1]];
            float4 p2 = svdat[b*V + fp[2]];
            float x0 = p0.x, y0 = p0.y, z0 = p0.z;
            float x1 = p1.x, y1 = p1.y, z1 = p1.z;
            float x2 = p2.x, y2 = p2.y, z2 = p2.z;
            float e1x = x1 - x0, e1y = y1 - y0;
            float e2x = x2 - x0, e2y = y2 - y0;
            float den = e1x*e2y - e2x*e1y;
            bool valid = fabsf(den) > 1e-8f;
            float dens = valid ? den : 1.0f;
            bool front = fminf(z0, fminf(z1, z2)) > 1e-9f;
            bool ok = valid && front;
            float A1 = e2y / dens, B1 = -e2x / dens;
            float C1 = -(x0*A1 + y0*B1);
            float A2 = -e1y / dens, B2 = e1x / dens;
            float C2 = -(x0*A2 + y0*B2);
            float A0 = -A1 - A2, B0 = -B1 - B2, C0 = 1.0f - C1 - C2;
            float rz0 = 1.0f/z0, rz1 = 1.0f/z1, rz2 = 1.0f/z2;
            float Az = A0*rz0 + A1*rz1 + A2*rz2;
            float Bz = B0*rz0 + B1*rz1 + B2*rz2;
            float Cz = C0*rz0 + C1*rz1 + C2*rz2;
            float xmn = fminf(x0, fminf(x1, x2)), xmx = fmaxf(x0, fmaxf(x1, x2));
            float ymn = fminf(y0, fminf(y1, y2)), ymx = fmaxf(y0, fmaxf(y1, y2));
            if (!ok) {
                A0 = B0 = 0.0f; C0 = -1.0f;
                A1 = B1 = C1 = 0.0f;
                A2 = B2 = C2 = 0.0f;
                Az = Bz = Cz = 0.0f;
                xmn = 1e30f; xmx = -1e30f; ymn = 1e30f; ymx = -1e30f;  // never overlaps
            }
            finner[(size_t)i*3 + 0] = make_float4(A0, A1, A2, Az);
            finner[(size_t)i*3 + 1] = make_float4(B0, B1, B2, Bz);
            finner[(size_t)i*3 + 2] = make_float4(C0, C1, C2, Cz);
            fbox[i] = make_float4(xmn, xmx, ymn, ymx);
            fepi[(size_t)i*3 + 0] = make_float4(x0, y0, z0, z1);
            fepi[(size_t)i*3 + 1] = make_float4(z2, e1x, e1y, e2x);
            fepi[(size_t)i*3 + 2] = make_float4(e2y, dens, 0.0f, 0.0f);
        }
    } else if (blk < NBF + NBT) {
        // ---- tanh(textures)
        int nt = F * 24;
        int stride = NBT * 256;
        for (int j = (blk - NBF)*256 + tid; j < nt; j += stride)
            texd[j] = tanhf(texin[j]);
    } else {
        // ---- zero cres + tile counters + global counter
        int stride = NBZ * 256;
        float4 z4 = make_float4(0.0f, 0.0f, 0.0f, 0.0f);
        for (int j = (blk - NBF - NBT)*256 + tid; j < nzero4; j += stride)
            zbase[j] = z4;
    }
}

__global__ __launch_bounds__(256, 8)
void k_raster(const float4* __restrict__ finner, const float4* __restrict__ fbox,
              const float4* __restrict__ fepi, const float* __restrict__ texd,
              const float* __restrict__ imref,
              unsigned long long* __restrict__ cres, int* __restrict__ tcnt,
              int* __restrict__ gcnt, double* __restrict__ partials,
              float* __restrict__ out, int B, int F, int S, int ntiles)
{
    __shared__ float4 sf[MAXFC * 3];
    __shared__ int    sidx[MAXFC];
    __shared__ int    scnt, samlast, sglast;
    __shared__ int    wbase[4];
    __shared__ double wsum[4];

    int tid    = threadIdx.x;
    int tileid = blockIdx.x >> 2;          // NCHUNK == 4
    int chunk  = blockIdx.x & (NCHUNK - 1);
    int tpi    = (S / TILE) * (S / TILE);  // tiles per image
    int b      = tileid / tpi;
    int tr     = tileid - b * tpi;
    int ty     = tr / (S / TILE);
    int tx     = tr - ty * (S / TILE);
    int px     = tx * TILE + (tid & (TILE - 1));
    int py     = ty * TILE + (tid >> 4);
    int SS     = S * S;
    int p      = b * SS + py * S + px;
    float Sf   = (float)S;
    float pxf  = (2.0f*px + 1.0f - Sf) / Sf;
    float pyf  = (2.0f*py + 1.0f - Sf) / Sf;
    float xlo  = (2.0f*(tx*TILE)          + 1.0f - Sf) / Sf;
    float xhi  = (2.0f*(tx*TILE + TILE-1) + 1.0f - Sf) / Sf;
    float ylo  = (2.0f*(ty*TILE)          + 1.0f - Sf) / Sf;
    float yhi  = (2.0f*(ty*TILE + TILE-1) + 1.0f - Sf) / Sf;

    int Fc = (F + NCHUNK - 1) / NCHUNK;
    int f0 = chunk * Fc;
    int f1 = min(F, f0 + Fc);
    int fcount = f1 - f0;

    if (tid == 0) scnt = 0;
    __syncthreads();

    // ---- bbox cull + ballot compaction (order-free: idx rides in the key)
    bool keep = false;
    if (tid < fcount) {
        float4 bb = fbox[(size_t)b*F + f0 + tid];  // (xmin,xmax,ymin,ymax)
        keep = !(bb.x > xhi || bb.y < xlo || bb.z > yhi || bb.w < ylo);
    }
    unsigned long long m = __ballot(keep);
    int lane = tid & 63, wid = tid >> 6;
    if (lane == 0) wbase[wid] = atomicAdd(&scnt, __popcll(m));
    __syncthreads();
    if (keep) {
        int pos = wbase[wid] + __popcll(m & ((1ULL << lane) - 1ULL));
        sidx[pos] = f0 + tid;
    }
    __syncthreads();
    int cnt = scnt;

    // ---- stage survivors' coefficients
    if (tid < cnt) {
        const float4* src = finner + ((size_t)b*F + sidx[tid]) * 3;
        sf[tid*3 + 0] = src[0];
        sf[tid*3 + 1] = src[1];
        sf[tid*3 + 2] = src[2];
    }
    __syncthreads();

    // ---- inner loop over surviving faces
    float best = 1e-9f;    // invz > EPS gate
    int jbest  = -1;
    #pragma unroll 2
    for (int j = 0; j < cnt; ++j) {
        float4 Av = sf[j*3 + 0];
        float4 Bv = sf[j*3 + 1];
        float4 Cv = sf[j*3 + 2];
        float w0 = fmaf(pxf, Av.x, fmaf(pyf, Bv.x, Cv.x));
        float w1 = fmaf(pxf, Av.y, fmaf(pyf, Bv.y, Cv.y));
        float w2 = fmaf(pxf, Av.z, fmaf(pyf, Bv.z, Cv.z));
        float iz = fmaf(pxf, Av.w, fmaf(pyf, Bv.w, Cv.w));
        float mn = fminf(w0, fminf(w1, w2));
        bool upd = (mn >= 0.0f) && (iz > best);
        best  = upd ? iz : best;
        jbest = upd ? j  : jbest;
    }
    if (jbest >= 0) {
        unsigned int bidx = (unsigned int)sidx[jbest];
        unsigned long long pk =
            ((unsigned long long)__float_as_uint(best) << 32) |
            (unsigned long long)(~bidx);
        atomicMax(&cres[p], pk);
    }

    // ---- last chunk block for this tile does the merge/epilogue
    __threadfence();
    __syncthreads();
    if (tid == 0) samlast = (atomicAdd(&tcnt[tileid], 1) == NCHUNK - 1);
    __syncthreads();
    if (!samlast) return;

    unsigned long long pk =
        __hip_atomic_load(&cres[p], __ATOMIC_ACQUIRE, __HIP_MEMORY_SCOPE_AGENT);
    float bz  = __uint_as_float((unsigned int)(pk >> 32));
    int bidx  = (int)(~(unsigned int)pk);
    bool hit  = bz > 1e-9f;
    if (!hit) bidx = 0;                 // argmin of all-inf = 0

    const float4* fe = fepi + (size_t)(b*F + bidx) * 3;
    float4 e0 = fe[0], e1 = fe[1], e2 = fe[2];
    float X0 = e0.x, Y0 = e0.y, Z0 = e0.z, Z1 = e0.w;
    float Z2 = e1.x, E1x = e1.y, E1y = e1.z, E2x = e1.w;
    float E2y = e2.x, D = e2.y;
    float dxp = pxf - X0, dyp = pyf - Y0;
    float W1 = (dxp*E2y - dyp*E2x) / D;
    float W2 = (E1x*dyp - E1y*dxp) / D;
    float W0 = 1.0f - W1 - W2;
    float q0 = W0 / Z0, q1 = W1 / Z1, q2 = W2 / Z2;
    float iz = fmaxf(q0 + q1 + q2, 1e-9f);
    float wp0 = fminf(fmaxf(q0 / iz, 0.0f), 1.0f);
    float wp1 = fminf(fmaxf(q1 / iz, 0.0f), 1.0f);
    float wp2 = fminf(fmaxf(q2 / iz, 0.0f), 1.0f);
    const float* T = texd + (size_t)bidx * 24;
    float hitf = hit ? 1.0f : 0.0f;
    float a0l = 1.0f - wp0, a0h = wp0;
    float a1l = 1.0f - wp1, a1h = wp1;
    float a2l = 1.0f - wp2, a2h = wp2;
    float s = 0.0f;
    #pragma unroll
    for (int cc = 0; cc < 3; ++cc) {
        float col =
            a0l*(a1l*(a2l*T[0  + cc] + a2h*T[3  + cc]) + a1h*(a2l*T[6  + cc] + a2h*T[9  + cc])) +
            a0h*(a1l*(a2l*T[12 + cc] + a2h*T[15 + cc]) + a1h*(a2l*T[18 + cc] + a2h*T[21 + cc]));
        col *= hitf;
        float r = imref[(((size_t)b*3 + cc)*S + py)*S + px];
        float d = col - r;
        s = fmaf(d, d, s);
    }

    double acc = (double)s;
    #pragma unroll
    for (int off = 32; off > 0; off >>= 1)
        acc += __shfl_down(acc, off, 64);
    if (lane == 0) wsum[wid] = acc;
    __syncthreads();
    if (tid == 0) {
        partials[tileid] = wsum[0] + wsum[1] + wsum[2] + wsum[3];
        __threadfence();
        sglast = (atomicAdd(gcnt, 1) == ntiles - 1);
    }
    __syncthreads();
    if (!sglast) return;

    // ---- very last tile: final reduction
    double a = 0.0;
    for (int i = tid; i < ntiles; i += 256)
        a += __hip_atomic_load(&partials[i], __ATOMIC_ACQUIRE, __HIP_MEMORY_SCOPE_AGENT);
    #pragma unroll
    for (int off = 32; off > 0; off >>= 1)
        a += __shfl_down(a, off, 64);
    __syncthreads();           // wsum reuse
    if (lane == 0) wsum[wid] = a;
    __syncthreads();
    if (tid == 0) out[0] = (float)(wsum[0] + wsum[1] + wsum[2] + wsum[3]);
}

extern "C" void kernel_launch(void* const* d_in, const int* in_sizes, int n_in,
                              void* d_out, int out_size, void* d_ws, size_t ws_size,
                              hipStream_t stream)
{
    const float* verts = (const float*)d_in[0];
    const int*   faces = (const int*)d_in[1];
    const float* Kmat  = (const float*)d_in[2];
    const float* Rmat  = (const float*)d_in[3];
    const float* tvec  = (const float*)d_in[4];
    const float* texin = (const float*)d_in[5];
    const float* imref = (const float*)d_in[6];

    int B = in_sizes[2] / 9;                    // K is (B,3,3)
    int V = in_sizes[0] / (3 * B);
    int F = in_sizes[1] / (3 * B);
    long ss = in_sizes[6] / (3L * B);           // image_ref is (B,3,S,S)
    int S = (int)(sqrt((double)ss) + 0.5);
    int npix   = B * S * S;
    int ntiles = B * (S / TILE) * (S / TILE);

    char* ws = (char*)d_ws;
    size_t off = 0;
    double* partials = (double*)(ws + off); off += (size_t)ntiles * 8;
    float4* finner   = (float4*)(ws + off); off += (size_t)B*F*48;
    float4* fepi     = (float4*)(ws + off); off += (size_t)B*F*48;
    float4* fbox     = (float4*)(ws + off); off += (size_t)B*F*16;
    float*  texd     = (float*)(ws + off);  off += (size_t)F*96;
    off = (off + 15) & ~(size_t)15;
    unsigned long long* cres = (unsigned long long*)(ws + off);
    size_t zoff = off;                      off += (size_t)npix * 8;
    int* tcnt = (int*)(ws + off);           off += (size_t)ntiles * 4;
    int* gcnt = (int*)(ws + off);           off += 16;
    int nzero4 = (int)((off - zoff + 15) / 16);   // cres + tcnt + gcnt as float4s
    float4* zbase = (float4*)(ws + zoff);

    int NBF = (B*F + 255) / 256;
    int NBT = 8;
    int NBZ = 32;
    k_prep<<<NBF + NBT + NBZ, 256, 0, stream>>>(verts, faces, Kmat, Rmat, tvec,
        texin, finner, fepi, fbox, texd, zbase, nzero4, B, V, F, S, NBF, NBT, NBZ);
    k_raster<<<ntiles * NCHUNK, 256, 0, stream>>>(finner, fbox, fepi, texd, imref,
        cres, tcnt, gcnt, partials, (float*)d_out, B, F, S, ntiles);
}

// Round 4
// 92.272 us; speedup vs baseline: 2.8225x; 2.8225x over previous
//
#include <hip/hip_runtime.h>
#include <math.h>

// Differentiable-rasterizer forward: scalar sum((render - ref)^2).
// B=2, V=512, F=768, S=256 (derived from in_sizes at runtime).
//
// R4: R3's in-kernel merge (device-scope fences + agent acquire loads per
// tile) caused L2 invalidation storms -> 188us @ 2.9% VALU. Revert to
// kernel-boundary synchronization (R2 structure) but keep the bbox cull:
//   k_prep   : face coeffs + bbox + tanh + zero cres   (46 parallel blocks)
//   k_raster : 512 tiles x 4 chunks = 2048 blocks (8/CU); ballot-compact
//              culled faces (~21/chunk avg), in-register packed-u64 best
//              (exact argmin-first-tie), one relaxed atomicMax per hit px
//   k_merge  : per-pixel epilogue (reference-exact) -> f64 partials
//   k_final  : reduce partials -> out[0]

#define NCHUNK 4
#define MAXFC  256   // faces per chunk (F/NCHUNK <= 256)
#define TILE   16

__global__ __launch_bounds__(256)
void k_prep(const float* __restrict__ verts, const int* __restrict__ faces,
            const float* __restrict__ Kmat, const float* __restrict__ Rmat,
            const float* __restrict__ tvec, const float* __restrict__ texin,
            float4* __restrict__ finner, float4* __restrict__ fepi,
            float4* __restrict__ fbox, float* __restrict__ texd,
            float4* __restrict__ zbase, int nzero4,
            int B, int V, int F, int S, int NBF, int NBT, int NBZ)
{
    int blk = blockIdx.x, tid = threadIdx.x;
    if (blk < NBF) {
        __shared__ float4 svdat[1024];      // B*V <= 1024 here
        int nv = B * V;
        for (int i = tid; i < nv && i < 1024; i += 256) {
            int b = i / V;
            const float* vp = verts + (size_t)i * 3;
            float vx = vp[0], vy = vp[1], vz = vp[2];
            const float* R  = Rmat + b * 9;
            const float* Kb = Kmat + b * 9;
            const float* tb = tvec + b * 3;
            float c0 = R[0]*vx + R[1]*vy + R[2]*vz + tb[0];
            float c1 = R[3]*vx + R[4]*vy + R[5]*vz + tb[1];
            float c2 = R[6]*vx + R[7]*vy + R[8]*vz + tb[2];
            float z  = c2;
            float zd = z + 1e-9f;
            float xh = c0 / zd;
            float yh = c1 / zd;
            float p0 = xh*Kb[0] + yh*Kb[1] + Kb[2];
            float p1 = xh*Kb[3] + yh*Kb[4] + Kb[5];
            float Sf = (float)S;
            float u = 2.0f * (p0 - 0.5f*Sf) / Sf;
            float v = 2.0f * ((Sf - p1) - 0.5f*Sf) / Sf;
            svdat[i] = make_float4(u, v, z, 0.0f);
        }
        __syncthreads();
        int i = blk * 256 + tid;
        if (i < B * F) {
            int b = i / F;
            const int* fp = faces + (size_t)i * 3;
            float4 p0 = svdat[b*V + fp[0]];
            float4 p1 = svdat[b*V + fp[1]];
            float4 p2 = svdat[b*V + fp[2]];
            float x0 = p0.x, y0 = p0.y, z0 = p0.z;
            float x1 = p1.x, y1 = p1.y, z1 = p1.z;
            float x2 = p2.x, y2 = p2.y, z2 = p2.z;
            float e1x = x1 - x0, e1y = y1 - y0;
            float e2x = x2 - x0, e2y = y2 - y0;
            float den = e1x*e2y - e2x*e1y;
            bool valid = fabsf(den) > 1e-8f;
            float dens = valid ? den : 1.0f;
            bool front = fminf(z0, fminf(z1, z2)) > 1e-9f;
            bool ok = valid && front;
            float A1 = e2y / dens, B1 = -e2x / dens;
            float C1 = -(x0*A1 + y0*B1);
            float A2 = -e1y / dens, B2 = e1x / dens;
            float C2 = -(x0*A2 + y0*B2);
            float A0 = -A1 - A2, B0 = -B1 - B2, C0 = 1.0f - C1 - C2;
            float rz0 = 1.0f/z0, rz1 = 1.0f/z1, rz2 = 1.0f/z2;
            float Az = A0*rz0 + A1*rz1 + A2*rz2;
            float Bz = B0*rz0 + B1*rz1 + B2*rz2;
            float Cz = C0*rz0 + C1*rz1 + C2*rz2;
            float xmn = fminf(x0, fminf(x1, x2)), xmx = fmaxf(x0, fmaxf(x1, x2));
            float ymn = fminf(y0, fminf(y1, y2)), ymx = fmaxf(y0, fmaxf(y1, y2));
            if (!ok) {
                A0 = B0 = 0.0f; C0 = -1.0f;
                A1 = B1 = C1 = 0.0f;
                A2 = B2 = C2 = 0.0f;
                Az = Bz = Cz = 0.0f;
                xmn = 1e30f; xmx = -1e30f; ymn = 1e30f; ymx = -1e30f;  // culled always
            }
            finner[(size_t)i*3 + 0] = make_float4(A0, A1, A2, Az);
            finner[(size_t)i*3 + 1] = make_float4(B0, B1, B2, Bz);
            finner[(size_t)i*3 + 2] = make_float4(C0, C1, C2, Cz);
            fbox[i] = make_float4(xmn, xmx, ymn, ymx);
            fepi[(size_t)i*3 + 0] = make_float4(x0, y0, z0, z1);
            fepi[(size_t)i*3 + 1] = make_float4(z2, e1x, e1y, e2x);
            fepi[(size_t)i*3 + 2] = make_float4(e2y, dens, 0.0f, 0.0f);
        }
    } else if (blk < NBF + NBT) {
        int nt = F * 24;
        int stride = NBT * 256;
        for (int j = (blk - NBF)*256 + tid; j < nt; j += stride)
            texd[j] = tanhf(texin[j]);
    } else {
        int stride = NBZ * 256;
        float4 z4 = make_float4(0.0f, 0.0f, 0.0f, 0.0f);
        for (int j = (blk - NBF - NBT)*256 + tid; j < nzero4; j += stride)
            zbase[j] = z4;
    }
}

__global__ __launch_bounds__(256, 8)
void k_raster(const float4* __restrict__ finner, const float4* __restrict__ fbox,
              unsigned long long* __restrict__ cres, int B, int F, int S)
{
    __shared__ float4   sf[MAXFC * 3];     // 12 KB
    __shared__ unsigned snidx[MAXFC];      // ~fidx of survivors
    __shared__ int      scnt;
    __shared__ int      wbase[4];

    int tid    = threadIdx.x;
    int tileid = blockIdx.x >> 2;          // NCHUNK == 4
    int chunk  = blockIdx.x & (NCHUNK - 1);
    int tpi    = (S / TILE) * (S / TILE);
    int b      = tileid / tpi;
    int tr     = tileid - b * tpi;
    int ty     = tr / (S / TILE);
    int tx     = tr - ty * (S / TILE);
    int px     = tx * TILE + (tid & (TILE - 1));
    int py     = ty * TILE + (tid >> 4);
    int p      = b * S * S + py * S + px;
    float Sf   = (float)S;
    float pxf  = (2.0f*px + 1.0f - Sf) / Sf;
    float pyf  = (2.0f*py + 1.0f - Sf) / Sf;
    float xlo  = (2.0f*(tx*TILE)          + 1.0f - Sf) / Sf;
    float xhi  = (2.0f*(tx*TILE + TILE-1) + 1.0f - Sf) / Sf;
    float ylo  = (2.0f*(ty*TILE)          + 1.0f - Sf) / Sf;
    float yhi  = (2.0f*(ty*TILE + TILE-1) + 1.0f - Sf) / Sf;

    int Fc = (F + NCHUNK - 1) / NCHUNK;
    int f0 = chunk * Fc;
    int f1 = min(F, f0 + Fc);
    int fcount = f1 - f0;

    if (tid == 0) scnt = 0;
    __syncthreads();

    // bbox cull + ballot compaction (order-free: face idx rides in the key)
    bool keep = false;
    if (tid < fcount) {
        float4 bb = fbox[(size_t)b*F + f0 + tid];   // (xmin,xmax,ymin,ymax)
        keep = !(bb.x > xhi || bb.y < xlo || bb.z > yhi || bb.w < ylo);
    }
    unsigned long long m = __ballot(keep);
    int lane = tid & 63, wid = tid >> 6;
    if (lane == 0) wbase[wid] = atomicAdd(&scnt, __popcll(m));
    __syncthreads();
    if (keep) {
        int pos = wbase[wid] + __popcll(m & ((1ULL << lane) - 1ULL));
        snidx[pos] = ~(unsigned)(f0 + tid);
    }
    __syncthreads();
    int cnt = scnt;

    // stage survivors' coefficients
    if (tid < cnt) {
        const float4* src = finner + ((size_t)b*F + (unsigned)~snidx[tid]) * 3;
        sf[tid*3 + 0] = src[0];
        sf[tid*3 + 1] = src[1];
        sf[tid*3 + 2] = src[2];
    }
    __syncthreads();

    // inner loop: packed key (izbits<<32)|~fidx, max == argmin(depth) w/
    // first-index tie-break; init with iz==EPS,~idx=all-ones => strict iz>EPS
    const unsigned long long initpk =
        ((unsigned long long)__float_as_uint(1e-9f) << 32) | 0xFFFFFFFFull;
    unsigned long long bestpk = initpk;
    #pragma unroll 2
    for (int j = 0; j < cnt; ++j) {
        float4 Av = sf[j*3 + 0];
        float4 Bv = sf[j*3 + 1];
        float4 Cv = sf[j*3 + 2];
        float w0 = fmaf(pxf, Av.x, fmaf(pyf, Bv.x, Cv.x));
        float w1 = fmaf(pxf, Av.y, fmaf(pyf, Bv.y, Cv.y));
        float w2 = fmaf(pxf, Av.z, fmaf(pyf, Bv.z, Cv.z));
        float iz = fmaf(pxf, Av.w, fmaf(pyf, Bv.w, Cv.w));
        float mn = fminf(w0, fminf(w1, w2));
        unsigned long long pk =
            ((unsigned long long)__float_as_uint(iz) << 32) |
            (unsigned long long)snidx[j];
        bool upd = (mn >= 0.0f) && (pk > bestpk);
        bestpk = upd ? pk : bestpk;
    }
    if (bestpk != initpk)
        atomicMax(&cres[p], bestpk);       // relaxed device atomic: cheap
}

__global__ __launch_bounds__(256)
void k_merge(const unsigned long long* __restrict__ cres,
             const float4* __restrict__ fepi, const float* __restrict__ texd,
             const float* __restrict__ imref, double* __restrict__ partials,
             int B, int F, int S)
{
    int tid = threadIdx.x;
    int p   = blockIdx.x * 256 + tid;
    int SS  = S * S;
    int b   = p / SS;
    int rem = p - b * SS;
    int py  = rem / S;
    int px  = rem - py * S;
    float Sf  = (float)S;
    float pxf = (2.0f*px + 1.0f - Sf) / Sf;
    float pyf = (2.0f*py + 1.0f - Sf) / Sf;

    unsigned long long pk = cres[p];
    float bz  = __uint_as_float((unsigned int)(pk >> 32));
    int bidx  = (int)(~(unsigned int)pk);
    bool hit  = bz > 1e-9f;
    if (!hit) bidx = 0;                    // argmin of all-inf = 0

    const float4* fe = fepi + (size_t)(b*F + bidx) * 3;
    float4 e0 = fe[0], e1 = fe[1], e2 = fe[2];
    float X0 = e0.x, Y0 = e0.y, Z0 = e0.z, Z1 = e0.w;
    float Z2 = e1.x, E1x = e1.y, E1y = e1.z, E2x = e1.w;
    float E2y = e2.x, D = e2.y;
    float dxp = pxf - X0, dyp = pyf - Y0;
    float W1 = (dxp*E2y - dyp*E2x) / D;
    float W2 = (E1x*dyp - E1y*dxp) / D;
    float W0 = 1.0f - W1 - W2;
    float q0 = W0 / Z0, q1 = W1 / Z1, q2 = W2 / Z2;
    float iz = fmaxf(q0 + q1 + q2, 1e-9f);
    float wp0 = fminf(fmaxf(q0 / iz, 0.0f), 1.0f);
    float wp1 = fminf(fmaxf(q1 / iz, 0.0f), 1.0f);
    float wp2 = fminf(fmaxf(q2 / iz, 0.0f), 1.0f);
    const float* T = texd + (size_t)bidx * 24;
    float hitf = hit ? 1.0f : 0.0f;
    float a0l = 1.0f - wp0, a0h = wp0;
    float a1l = 1.0f - wp1, a1h = wp1;
    float a2l = 1.0f - wp2, a2h = wp2;
    float s = 0.0f;
    #pragma unroll
    for (int cc = 0; cc < 3; ++cc) {
        float col =
            a0l*(a1l*(a2l*T[0  + cc] + a2h*T[3  + cc]) + a1h*(a2l*T[6  + cc] + a2h*T[9  + cc])) +
            a0h*(a1l*(a2l*T[12 + cc] + a2h*T[15 + cc]) + a1h*(a2l*T[18 + cc] + a2h*T[21 + cc]));
        col *= hitf;
        float r = imref[(((size_t)b*3 + cc)*S + py)*S + px];
        float d = col - r;
        s = fmaf(d, d, s);
    }

    double acc = (double)s;
    #pragma unroll
    for (int off = 32; off > 0; off >>= 1)
        acc += __shfl_down(acc, off, 64);
    __shared__ double wsum[4];
    int lane = tid & 63, wid = tid >> 6;
    if (lane == 0) wsum[wid] = acc;
    __syncthreads();
    if (tid == 0) partials[blockIdx.x] = wsum[0] + wsum[1] + wsum[2] + wsum[3];
}

__global__ void k_final(const double* __restrict__ partials, float* __restrict__ out, int n)
{
    int tid = threadIdx.x;
    double a = 0.0;
    for (int i = tid; i < n; i += 256) a += partials[i];
    #pragma unroll
    for (int off = 32; off > 0; off >>= 1)
        a += __shfl_down(a, off, 64);
    __shared__ double wsum[4];
    int lane = tid & 63, wid = tid >> 6;
    if (lane == 0) wsum[wid] = a;
    __syncthreads();
    if (tid == 0) out[0] = (float)(wsum[0] + wsum[1] + wsum[2] + wsum[3]);
}

extern "C" void kernel_launch(void* const* d_in, const int* in_sizes, int n_in,
                              void* d_out, int out_size, void* d_ws, size_t ws_size,
                              hipStream_t stream)
{
    const float* verts = (const float*)d_in[0];
    const int*   faces = (const int*)d_in[1];
    const float* Kmat  = (const float*)d_in[2];
    const float* Rmat  = (const float*)d_in[3];
    const float* tvec  = (const float*)d_in[4];
    const float* texin = (const float*)d_in[5];
    const float* imref = (const float*)d_in[6];

    int B = in_sizes[2] / 9;                    // K is (B,3,3)
    int V = in_sizes[0] / (3 * B);
    int F = in_sizes[1] / (3 * B);
    long ss = in_sizes[6] / (3L * B);           // image_ref is (B,3,S,S)
    int S = (int)(sqrt((double)ss) + 0.5);
    int npix   = B * S * S;
    int ntiles = B * (S / TILE) * (S / TILE);
    int nmb    = npix / 256;                    // merge blocks

    char* ws = (char*)d_ws;
    size_t off = 0;
    double* partials = (double*)(ws + off); off += (size_t)nmb * 8;
    float4* finner   = (float4*)(ws + off); off += (size_t)B*F*48;
    float4* fepi     = (float4*)(ws + off); off += (size_t)B*F*48;
    float4* fbox     = (float4*)(ws + off); off += (size_t)B*F*16;
    float*  texd     = (float*)(ws + off);  off += (size_t)F*96;
    off = (off + 15) & ~(size_t)15;
    unsigned long long* cres = (unsigned long long*)(ws + off);
    int nzero4 = npix / 2;                      // npix*8 bytes as float4s
    float4* zbase = (float4*)cres;

    int NBF = (B*F + 255) / 256;
    int NBT = 8;
    int NBZ = 32;
    k_prep<<<NBF + NBT + NBZ, 256, 0, stream>>>(verts, faces, Kmat, Rmat, tvec,
        texin, finner, fepi, fbox, texd, zbase, nzero4, B, V, F, S, NBF, NBT, NBZ);
    k_raster<<<ntiles * NCHUNK, 256, 0, stream>>>(finner, fbox, cres, B, F, S);
    k_merge<<<nmb, 256, 0, stream>>>(cres, fepi, texd, imref, partials, B, F, S);
    k_final<<<1, 256, 0, stream>>>(partials, (float*)d_out, nmb);
}